// Round 1
// baseline (310.435 us; speedup 1.0000x reference)
//
#include <hip/hip_runtime.h>

#define MIN_NORM 1e-15f
#define MAXN (1.0f - 4e-3f)

typedef __attribute__((ext_vector_type(8))) short short8;   // 8 bf16 (4 VGPRs)
typedef __attribute__((ext_vector_type(4))) float f32x4;    // 4 fp32 acc

__device__ __forceinline__ float bf2f(unsigned short u) {
  union { unsigned int i; float f; } c; c.i = ((unsigned int)u) << 16; return c.f;
}
__device__ __forceinline__ unsigned short f2bf(float f) {
  union { float f; unsigned int i; } c; c.f = f;
  unsigned int r = c.i + 0x7FFFu + ((c.i >> 16) & 1u);
  return (unsigned short)(r >> 16);
}
__device__ __forceinline__ float wave_sum(float v) {
#pragma unroll
  for (int off = 32; off > 0; off >>= 1) v += __shfl_xor(v, off, 64);
  return v;
}
__device__ __forceinline__ float gsum16(float v) {  // sum over 16-lane group
#pragma unroll
  for (int off = 8; off > 0; off >>= 1) v += __shfl_xor(v, off, 64);
  return v;
}

// ---------------- prep: rs[i] + bf16 cast of x; W->bf16 (blocks<64); hb (block 64) --
__global__ __launch_bounds__(256) void k_prep(const float* __restrict__ x,
                                              const float* __restrict__ W,
                                              const float* __restrict__ b_lin,
                                              float* __restrict__ rs,
                                              unsigned short* __restrict__ xb,
                                              unsigned short* __restrict__ Wb,
                                              float* __restrict__ hb,
                                              float* __restrict__ hb2, int N) {
  int row = blockIdx.x * 4 + (threadIdx.x >> 6);
  int lane = threadIdx.x & 63;
  float4 u = *(const float4*)(x + (size_t)row * 256 + lane * 4);
  ushort4 st;
  st.x = f2bf(u.x); st.y = f2bf(u.y); st.z = f2bf(u.z); st.w = f2bf(u.w);
  *(ushort4*)(xb + (size_t)row * 256 + lane * 4) = st;
  float s = wave_sum(u.x * u.x + u.y * u.y + u.z * u.z + u.w * u.w);
  if (lane == 0) {
    float n = fmaxf(sqrtf(s), MIN_NORM);
    rs[row] = atanhf(fminf(n, 1.0f - 1e-7f)) / n;
  }
  // W -> bf16, 64 blocks x 256 thr x 4 elems = 65536
  if (blockIdx.x < 64) {
    int idx = (blockIdx.x * 256 + threadIdx.x) * 4;
    float4 wv = *(const float4*)(W + idx);
    ushort4 ws;
    ws.x = f2bf(wv.x); ws.y = f2bf(wv.y); ws.z = f2bf(wv.z); ws.w = f2bf(wv.w);
    *(ushort4*)(Wb + idx) = ws;
  }
  // hb = proj(expmap0(b_lin)) + |hb|^2, one wave
  if (blockIdx.x == 64 && threadIdx.x < 64) {
    float4 b4 = ((const float4*)b_lin)[lane];
    float bx = b4.x, by = b4.y, bz = b4.z, bw = b4.w;
    float sb = wave_sum(bx * bx + by * by + bz * bz + bw * bw);
    float n1 = fmaxf(sqrtf(sb), MIN_NORM);
    float t = tanhf(n1) / n1;
    bx *= t; by *= t; bz *= t; bw *= t;
    float s2 = wave_sum(bx * bx + by * by + bz * bz + bw * bw);
    float n2 = fmaxf(sqrtf(s2), MIN_NORM);
    if (n2 > MAXN) { float f = MAXN / n2; bx *= f; by *= f; bz *= f; bw *= f; }
    float4 o; o.x = bx; o.y = by; o.z = bz; o.w = bw;
    ((float4*)hb)[lane] = o;
    float s3 = wave_sum(bx * bx + by * by + bz * bz + bw * bw);
    if (lane == 0) *hb2 = s3;
  }
}

// ---------------- fused MFMA GEMM + hyperbolic chain + attention partials ----------
// Block: 256 thr (4 waves), 64 Lmat rows. kk-outer / jt-inner: 16 independent accs,
// B prefetched 8 frags at a time => ILP hides L2 latency on Wb reads.
__global__ __launch_bounds__(256) void k_gemmhyp(const unsigned short* __restrict__ xb,
                                                 const unsigned short* __restrict__ Wb,
                                                 const float* __restrict__ rs,
                                                 const float* __restrict__ hb,
                                                 const float* __restrict__ hb2p,
                                                 const float* __restrict__ att,
                                                 unsigned short* __restrict__ L,
                                                 float* __restrict__ s_i,
                                                 float* __restrict__ s_j,
                                                 int M, int NQ) {
  int tid = threadIdx.x;
  int wv = tid >> 6, lane = tid & 63, qd = lane >> 4, lc = lane & 15;
  int i0 = blockIdx.x * 64;
  int arow = i0 + wv * 16 + lc;
  if (arow >= M) arow = M - 1;  // clamp; stores guarded later
  short8 af[8];
#pragma unroll
  for (int kk = 0; kk < 8; ++kk)
    af[kk] = *(const short8*)(xb + (size_t)arow * 256 + kk * 32 + qd * 8);
  f32x4 acc[16];
#pragma unroll
  for (int jt = 0; jt < 16; ++jt) acc[jt] = (f32x4){0.f, 0.f, 0.f, 0.f};
#pragma unroll
  for (int kk = 0; kk < 8; ++kk) {
#pragma unroll
    for (int half = 0; half < 2; ++half) {
      short8 bf[8];
#pragma unroll
      for (int j = 0; j < 8; ++j)
        bf[j] = *(const short8*)(Wb + (size_t)((half * 8 + j) * 16 + lc) * 256 + kk * 32 + qd * 8);
#pragma unroll
      for (int j = 0; j < 8; ++j)
        acc[half * 8 + j] =
            __builtin_amdgcn_mfma_f32_16x16x32_bf16(af[kk], bf[j], acc[half * 8 + j], 0, 0, 0);
    }
  }
  // constants for the chain
  float y2 = *hb2p;
  float hbreg[16];
#pragma unroll
  for (int jt = 0; jt < 16; ++jt) hbreg[jt] = hb[jt * 16 + lc];

#pragma unroll
  for (int r = 0; r < 4; ++r) {
    int row_r = i0 + wv * 16 + qd * 4 + r;
    bool valid = row_r < M;
    int rr = valid ? row_r : M - 1;
    float rsv = rs[rr];
    float v[16];
    float ss = 0.0f;
#pragma unroll
    for (int jt = 0; jt < 16; ++jt) { v[jt] = rsv * acc[jt][r]; ss += v[jt] * v[jt]; }
    ss = gsum16(ss);
    // expmap0 + proj (analytic norms)
    float n1 = fmaxf(sqrtf(ss), MIN_NORM);
    float e1 = tanhf(n1) / n1;
    float n2 = e1 * n1;                       // |expmap0(v)|
    float f2 = (n2 > MAXN) ? MAXN / n2 : 1.0f;
    float e12 = e1 * f2;
    float nx = n2 * f2;                       // |proj(...)|
    float x2 = nx * nx;
#pragma unroll
    for (int jt = 0; jt < 16; ++jt) v[jt] *= e12;
    // mobius_add(v, hb)
    float xy = 0.0f;
#pragma unroll
    for (int jt = 0; jt < 16; ++jt) xy += v[jt] * hbreg[jt];
    xy = gsum16(xy);
    float c1 = 1.0f + 2.0f * xy + y2;
    float c2 = 1.0f - x2;
    float den = fmaxf(1.0f + 2.0f * xy + x2 * y2, MIN_NORM);
    float inv = 1.0f / den;
    float s3 = inv * inv * (c1 * c1 * x2 + 2.0f * c1 * c2 * xy + c2 * c2 * y2);
    float n3 = fmaxf(sqrtf(s3), MIN_NORM);
    float f3 = (n3 > MAXN) ? MAXN / n3 : 1.0f;
    float n4 = fmaxf(n3 * f3, MIN_NORM);      // |proj(z)| <= MAXN < 1-1e-7
    float sc = atanhf(n4) / n4;
    float g = inv * f3 * sc;
    float Lv[16];
#pragma unroll
    for (int jt = 0; jt < 16; ++jt) Lv[jt] = (c1 * v[jt] + c2 * hbreg[jt]) * g;
    // faithful head/node decode for this Lmat row
    int h_r = row_r / NQ;
    int q_r = row_r - h_r * NQ;
    if (valid) {
#pragma unroll
      for (int jt = 0; jt < 16; ++jt) {
        int n = q_r * 4 + (jt >> 2);
        int d = (jt & 3) * 16 + lc;
        L[(size_t)n * 256 + h_r * 64 + d] = f2bf(Lv[jt]);
      }
    }
    float pig[4], pjg[4];
#pragma unroll
    for (int g4 = 0; g4 < 4; ++g4) {
      float pi = 0.0f, pj = 0.0f;
#pragma unroll
      for (int t = 0; t < 4; ++t) {
        float a_i = att[h_r * 128 + t * 16 + lc];
        float a_j = att[h_r * 128 + 64 + t * 16 + lc];
        pi += Lv[g4 * 4 + t] * a_i;
        pj += Lv[g4 * 4 + t] * a_j;
      }
      pig[g4] = gsum16(pi);
      pjg[g4] = gsum16(pj);
    }
    if (valid && lc == 0) {
#pragma unroll
      for (int g4 = 0; g4 < 4; ++g4) {
        int n = q_r * 4 + g4;
        s_i[n * 4 + h_r] = pig[g4];
        s_j[n * 4 + h_r] = pjg[g4];
      }
    }
  }
}

// ---------------- CSR buckets (ushort slots): self-loop slot 0 ----------------
__global__ void k_init(int* __restrict__ cnt, unsigned short* __restrict__ slots, int N) {
  int n = blockIdx.x * blockDim.x + threadIdx.x;
  if (n < N) { cnt[n] = 1; slots[(size_t)n * 64] = (unsigned short)n; }
}
__global__ void k_fill(const int* __restrict__ ei, int* __restrict__ cnt,
                       unsigned short* __restrict__ slots, int E) {
  int e = blockIdx.x * blockDim.x + threadIdx.x;
  if (e < E) {
    int s = ei[e];
    int d = ei[E + e];
    int pos = atomicAdd(&cnt[d], 1);
    if (pos < 64) slots[(size_t)d * 64 + pos] = (unsigned short)s;
  }
}

// ---------------- aggregation + epilogue; block = q (4 nodes, 4 final rows) -------
__global__ __launch_bounds__(256) void HGATLayer_49246095016355_kernel(
    const unsigned short* __restrict__ L,
    const float* __restrict__ s_i,
    const float* __restrict__ s_j,
    const int* __restrict__ cnt,
    const unsigned short* __restrict__ slots,
    const float* __restrict__ b_conv,
    float* __restrict__ out, int N, int NQ) {
  int q = blockIdx.x;
  int w = threadIdx.x >> 6, lane = threadIdx.x & 63;
  int n = q * 4 + w;
  int deg = min(cnt[n], 64);
  float4 si4 = *(const float4*)(s_i + n * 4);
  // lane-parallel per-head scores for edge k=lane
  int src_l = 0;
  float4 a4 = {-1e30f, -1e30f, -1e30f, -1e30f};
  if (lane < deg) {
    src_l = slots[(size_t)n * 64 + lane];
    float4 sj4 = *(const float4*)(s_j + src_l * 4);
    float t0 = si4.x + sj4.x, t1 = si4.y + sj4.y, t2 = si4.z + sj4.z, t3 = si4.w + sj4.w;
    a4.x = (t0 > 0.f) ? t0 : 0.2f * t0;
    a4.y = (t1 > 0.f) ? t1 : 0.2f * t1;
    a4.z = (t2 > 0.f) ? t2 : 0.2f * t2;
    a4.w = (t3 > 0.f) ? t3 : 0.2f * t3;
  }
  float4 mx = a4;
#pragma unroll
  for (int off = 32; off > 0; off >>= 1) {
    mx.x = fmaxf(mx.x, __shfl_xor(mx.x, off, 64));
    mx.y = fmaxf(mx.y, __shfl_xor(mx.y, off, 64));
    mx.z = fmaxf(mx.z, __shfl_xor(mx.z, off, 64));
    mx.w = fmaxf(mx.w, __shfl_xor(mx.w, off, 64));
  }
  float4 p4 = {0.f, 0.f, 0.f, 0.f};
  if (lane < deg) {
    p4.x = __expf(a4.x - mx.x); p4.y = __expf(a4.y - mx.y);
    p4.z = __expf(a4.z - mx.z); p4.w = __expf(a4.w - mx.w);
  }
  float4 sm = p4;
#pragma unroll
  for (int off = 32; off > 0; off >>= 1) {
    sm.x += __shfl_xor(sm.x, off, 64);
    sm.y += __shfl_xor(sm.y, off, 64);
    sm.z += __shfl_xor(sm.z, off, 64);
    sm.w += __shfl_xor(sm.w, off, 64);
  }
  __shared__ int   s_src[4][64];
  __shared__ float s_w[4][64][4];
  s_src[w][lane] = src_l;
  *(float4*)&s_w[w][lane][0] = p4;  // same-wave produce/consume: no barrier needed
  int h = lane >> 4;
  float smh = (h == 0) ? sm.x : (h == 1) ? sm.y : (h == 2) ? sm.z : sm.w;
  // gather loop: 8-way unrolled, 8B/lane loads (full 512B row = all heads)
  f32x4 ac0 = {0,0,0,0}, ac1 = {0,0,0,0}, ac2 = {0,0,0,0}, ac3 = {0,0,0,0};
  int k = 0;
  for (; k + 7 < deg; k += 8) {
    int sA = s_src[w][k + 0], sB = s_src[w][k + 1];
    int sC = s_src[w][k + 2], sD = s_src[w][k + 3];
    int sE = s_src[w][k + 4], sF = s_src[w][k + 5];
    int sG = s_src[w][k + 6], sH = s_src[w][k + 7];
    ushort4 rA = *(const ushort4*)(L + (size_t)sA * 256 + lane * 4);
    ushort4 rB = *(const ushort4*)(L + (size_t)sB * 256 + lane * 4);
    ushort4 rC = *(const ushort4*)(L + (size_t)sC * 256 + lane * 4);
    ushort4 rD = *(const ushort4*)(L + (size_t)sD * 256 + lane * 4);
    ushort4 rE = *(const ushort4*)(L + (size_t)sE * 256 + lane * 4);
    ushort4 rF = *(const ushort4*)(L + (size_t)sF * 256 + lane * 4);
    ushort4 rG = *(const ushort4*)(L + (size_t)sG * 256 + lane * 4);
    ushort4 rH = *(const ushort4*)(L + (size_t)sH * 256 + lane * 4);
    float wA = s_w[w][k + 0][h], wB = s_w[w][k + 1][h];
    float wC = s_w[w][k + 2][h], wD = s_w[w][k + 3][h];
    float wE = s_w[w][k + 4][h], wF = s_w[w][k + 5][h];
    float wG = s_w[w][k + 6][h], wH = s_w[w][k + 7][h];
    ac0[0] = fmaf(wA, bf2f(rA.x), ac0[0]); ac0[1] = fmaf(wA, bf2f(rA.y), ac0[1]);
    ac0[2] = fmaf(wA, bf2f(rA.z), ac0[2]); ac0[3] = fmaf(wA, bf2f(rA.w), ac0[3]);
    ac1[0] = fmaf(wB, bf2f(rB.x), ac1[0]); ac1[1] = fmaf(wB, bf2f(rB.y), ac1[1]);
    ac1[2] = fmaf(wB, bf2f(rB.z), ac1[2]); ac1[3] = fmaf(wB, bf2f(rB.w), ac1[3]);
    ac2[0] = fmaf(wC, bf2f(rC.x), ac2[0]); ac2[1] = fmaf(wC, bf2f(rC.y), ac2[1]);
    ac2[2] = fmaf(wC, bf2f(rC.z), ac2[2]); ac2[3] = fmaf(wC, bf2f(rC.w), ac2[3]);
    ac3[0] = fmaf(wD, bf2f(rD.x), ac3[0]); ac3[1] = fmaf(wD, bf2f(rD.y), ac3[1]);
    ac3[2] = fmaf(wD, bf2f(rD.z), ac3[2]); ac3[3] = fmaf(wD, bf2f(rD.w), ac3[3]);
    ac0[0] = fmaf(wE, bf2f(rE.x), ac0[0]); ac0[1] = fmaf(wE, bf2f(rE.y), ac0[1]);
    ac0[2] = fmaf(wE, bf2f(rE.z), ac0[2]); ac0[3] = fmaf(wE, bf2f(rE.w), ac0[3]);
    ac1[0] = fmaf(wF, bf2f(rF.x), ac1[0]); ac1[1] = fmaf(wF, bf2f(rF.y), ac1[1]);
    ac1[2] = fmaf(wF, bf2f(rF.z), ac1[2]); ac1[3] = fmaf(wF, bf2f(rF.w), ac1[3]);
    ac2[0] = fmaf(wG, bf2f(rG.x), ac2[0]); ac2[1] = fmaf(wG, bf2f(rG.y), ac2[1]);
    ac2[2] = fmaf(wG, bf2f(rG.z), ac2[2]); ac2[3] = fmaf(wG, bf2f(rG.w), ac2[3]);
    ac3[0] = fmaf(wH, bf2f(rH.x), ac3[0]); ac3[1] = fmaf(wH, bf2f(rH.y), ac3[1]);
    ac3[2] = fmaf(wH, bf2f(rH.z), ac3[2]); ac3[3] = fmaf(wH, bf2f(rH.w), ac3[3]);
  }
  for (; k + 3 < deg; k += 4) {
    int sA = s_src[w][k + 0], sB = s_src[w][k + 1];
    int sC = s_src[w][k + 2], sD = s_src[w][k + 3];
    float wA = s_w[w][k + 0][h], wB = s_w[w][k + 1][h];
    float wC = s_w[w][k + 2][h], wD = s_w[w][k + 3][h];
    ushort4 rA = *(const ushort4*)(L + (size_t)sA * 256 + lane * 4);
    ushort4 rB = *(const ushort4*)(L + (size_t)sB * 256 + lane * 4);
    ushort4 rC = *(const ushort4*)(L + (size_t)sC * 256 + lane * 4);
    ushort4 rD = *(const ushort4*)(L + (size_t)sD * 256 + lane * 4);
    ac0[0] = fmaf(wA, bf2f(rA.x), ac0[0]); ac0[1] = fmaf(wA, bf2f(rA.y), ac0[1]);
    ac0[2] = fmaf(wA, bf2f(rA.z), ac0[2]); ac0[3] = fmaf(wA, bf2f(rA.w), ac0[3]);
    ac1[0] = fmaf(wB, bf2f(rB.x), ac1[0]); ac1[1] = fmaf(wB, bf2f(rB.y), ac1[1]);
    ac1[2] = fmaf(wB, bf2f(rB.z), ac1[2]); ac1[3] = fmaf(wB, bf2f(rB.w), ac1[3]);
    ac2[0] = fmaf(wC, bf2f(rC.x), ac2[0]); ac2[1] = fmaf(wC, bf2f(rC.y), ac2[1]);
    ac2[2] = fmaf(wC, bf2f(rC.z), ac2[2]); ac2[3] = fmaf(wC, bf2f(rC.w), ac2[3]);
    ac3[0] = fmaf(wD, bf2f(rD.x), ac3[0]); ac3[1] = fmaf(wD, bf2f(rD.y), ac3[1]);
    ac3[2] = fmaf(wD, bf2f(rD.z), ac3[2]); ac3[3] = fmaf(wD, bf2f(rD.w), ac3[3]);
  }
  for (; k < deg; ++k) {
    int sA = s_src[w][k];
    float wA = s_w[w][k][h];
    ushort4 rA = *(const ushort4*)(L + (size_t)sA * 256 + lane * 4);
    ac0[0] = fmaf(wA, bf2f(rA.x), ac0[0]); ac0[1] = fmaf(wA, bf2f(rA.y), ac0[1]);
    ac0[2] = fmaf(wA, bf2f(rA.z), ac0[2]); ac0[3] = fmaf(wA, bf2f(rA.w), ac0[3]);
  }
  float isum = 1.0f / fmaxf(smh, MIN_NORM);
  float4 bc4 = *(const float4*)(b_conv + w * 64 + (lane & 15) * 4);
  float v0 = fmaxf((ac0[0] + ac1[0] + ac2[0] + ac3[0]) * isum + bc4.x, 0.0f);
  float v1 = fmaxf((ac0[1] + ac1[1] + ac2[1] + ac3[1]) * isum + bc4.y, 0.0f);
  float v2 = fmaxf((ac0[2] + ac1[2] + ac2[2] + ac3[2]) * isum + bc4.z, 0.0f);
  float v3 = fmaxf((ac0[3] + ac1[3] + ac2[3] + ac3[3]) * isum + bc4.w, 0.0f);
  float ps = v0 * v0 + v1 * v1 + v2 * v2 + v3 * v3;
  ps = gsum16(ps);
  __shared__ float red[4][4];
  if ((lane & 15) == 0) red[w][h] = ps;
  __syncthreads();
  float tot = red[0][h] + red[1][h] + red[2][h] + red[3][h];
  float nraw = sqrtf(tot);
  float nc = fmaxf(nraw, MIN_NORM);
  float t = tanhf(nc) / nc;  // expmap0 scale
  float ny = fmaxf(t * nraw, MIN_NORM);
  float f = (ny > MAXN) ? (MAXN / ny) : 1.0f;
  float tf = t * f;
  float4 y; y.x = tf * v0; y.y = tf * v1; y.z = tf * v2; y.w = tf * v3;
  *(float4*)(out + (size_t)(h * NQ + q) * 256 + w * 64 + (lane & 15) * 4) = y;
}

extern "C" void kernel_launch(void* const* d_in, const int* in_sizes, int n_in,
                              void* d_out, int out_size, void* d_ws, size_t ws_size,
                              hipStream_t stream) {
  const float* x   = (const float*)d_in[0];
  const int*   ei  = (const int*)d_in[1];
  const float* W   = (const float*)d_in[2];
  const float* bl  = (const float*)d_in[3];
  const float* att = (const float*)d_in[4];
  const float* bc  = (const float*)d_in[5];
  float* out = (float*)d_out;

  const int N = in_sizes[0] / 256;  // 50000
  const int E = in_sizes[1] / 2;    // 800000
  const int NQ = N / 4;             // 12500

  // xb (bf16 x) staged in d_out: dead before the final kernel overwrites out
  unsigned short* xb = (unsigned short*)d_out;

  char* w = (char*)d_ws;
  unsigned short* L  = (unsigned short*)w; w += (size_t)N * 256 * 2;  // 25.6 MB node-major
  unsigned short* Wb = (unsigned short*)w; w += 65536 * 2;            // 128 KB
  float* s_i = (float*)w; w += (size_t)N * 4 * 4;
  float* s_j = (float*)w; w += (size_t)N * 4 * 4;
  float* rs  = (float*)w; w += (size_t)N * 4;
  float* hb  = (float*)w; w += 256 * 4;
  float* hb2 = (float*)w; w += 16;
  int* cnt   = (int*)w;   w += (size_t)N * 4;
  unsigned short* slots = (unsigned short*)w;  // N*64 ushort = 6.4 MB

  k_prep<<<N / 4, 256, 0, stream>>>(x, W, bl, rs, xb, Wb, hb, hb2, N);
  k_gemmhyp<<<(N + 63) / 64, 256, 0, stream>>>(xb, Wb, rs, hb, hb2, att, L, s_i, s_j, N, NQ);
  k_init<<<(N + 255) / 256, 256, 0, stream>>>(cnt, slots, N);
  k_fill<<<(E + 255) / 256, 256, 0, stream>>>(ei, cnt, slots, E);
  HGATLayer_49246095016355_kernel<<<NQ, 256, 0, stream>>>(L, s_i, s_j, cnt, slots, bc, out, N, NQ);
}

// Round 2
// 306.416 us; speedup vs baseline: 1.0131x; 1.0131x over previous
//
#include <hip/hip_runtime.h>

#define MIN_NORM 1e-15f
#define MAXN (1.0f - 4e-3f)

typedef __attribute__((ext_vector_type(8))) short short8;   // 8 bf16 (4 VGPRs)
typedef __attribute__((ext_vector_type(4))) float f32x4;    // 4 fp32 acc

__device__ __forceinline__ float bf2f(unsigned short u) {
  union { unsigned int i; float f; } c; c.i = ((unsigned int)u) << 16; return c.f;
}
__device__ __forceinline__ unsigned short f2bf(float f) {
  union { float f; unsigned int i; } c; c.f = f;
  unsigned int r = c.i + 0x7FFFu + ((c.i >> 16) & 1u);
  return (unsigned short)(r >> 16);
}
__device__ __forceinline__ float wave_sum(float v) {
#pragma unroll
  for (int off = 32; off > 0; off >>= 1) v += __shfl_xor(v, off, 64);
  return v;
}
__device__ __forceinline__ float gsum16(float v) {  // sum over 16-lane group
#pragma unroll
  for (int off = 8; off > 0; off >>= 1) v += __shfl_xor(v, off, 64);
  return v;
}

// ---------------- prep: rs[i] + bf16 cast of x; W->bf16 (blocks<64); hb (block 64)
// ---------------- also folds CSR init (cnt=1, self-loop in slot 0) ----------------
__global__ __launch_bounds__(256) void k_prep(const float* __restrict__ x,
                                              const float* __restrict__ W,
                                              const float* __restrict__ b_lin,
                                              float* __restrict__ rs,
                                              unsigned short* __restrict__ xb,
                                              unsigned short* __restrict__ Wb,
                                              float* __restrict__ hb,
                                              float* __restrict__ hb2,
                                              int* __restrict__ cnt,
                                              unsigned short* __restrict__ slots, int N) {
  int row = blockIdx.x * 4 + (threadIdx.x >> 6);
  int lane = threadIdx.x & 63;
  float4 u = *(const float4*)(x + (size_t)row * 256 + lane * 4);
  ushort4 st;
  st.x = f2bf(u.x); st.y = f2bf(u.y); st.z = f2bf(u.z); st.w = f2bf(u.w);
  *(ushort4*)(xb + (size_t)row * 256 + lane * 4) = st;
  float s = wave_sum(u.x * u.x + u.y * u.y + u.z * u.z + u.w * u.w);
  if (lane == 0) {
    float n = fmaxf(sqrtf(s), MIN_NORM);
    rs[row] = atanhf(fminf(n, 1.0f - 1e-7f)) / n;
  }
  // CSR init folded in: cnt=1, slot 0 = self loop
  int g = blockIdx.x * 256 + threadIdx.x;
  if (g < N) { cnt[g] = 1; slots[(size_t)g * 64] = (unsigned short)g; }
  // W -> bf16, 64 blocks x 256 thr x 4 elems = 65536
  if (blockIdx.x < 64) {
    int idx = (blockIdx.x * 256 + threadIdx.x) * 4;
    float4 wv = *(const float4*)(W + idx);
    ushort4 ws;
    ws.x = f2bf(wv.x); ws.y = f2bf(wv.y); ws.z = f2bf(wv.z); ws.w = f2bf(wv.w);
    *(ushort4*)(Wb + idx) = ws;
  }
  // hb = proj(expmap0(b_lin)) + |hb|^2, one wave
  if (blockIdx.x == 64 && threadIdx.x < 64) {
    float4 b4 = ((const float4*)b_lin)[lane];
    float bx = b4.x, by = b4.y, bz = b4.z, bw = b4.w;
    float sb = wave_sum(bx * bx + by * by + bz * bz + bw * bw);
    float n1 = fmaxf(sqrtf(sb), MIN_NORM);
    float t = tanhf(n1) / n1;
    bx *= t; by *= t; bz *= t; bw *= t;
    float s2 = wave_sum(bx * bx + by * by + bz * bz + bw * bw);
    float n2 = fmaxf(sqrtf(s2), MIN_NORM);
    if (n2 > MAXN) { float f = MAXN / n2; bx *= f; by *= f; bz *= f; bw *= f; }
    float4 o; o.x = bx; o.y = by; o.z = bz; o.w = bw;
    ((float4*)hb)[lane] = o;
    float s3 = wave_sum(bx * bx + by * by + bz * bz + bw * bw);
    if (lane == 0) *hb2 = s3;
  }
}

// ---------------- fused MFMA GEMM + hyperbolic chain + attention partials ----------
__global__ __launch_bounds__(256) void k_gemmhyp(const unsigned short* __restrict__ xb,
                                                 const unsigned short* __restrict__ Wb,
                                                 const float* __restrict__ rs,
                                                 const float* __restrict__ hb,
                                                 const float* __restrict__ hb2p,
                                                 const float* __restrict__ att,
                                                 unsigned short* __restrict__ L,
                                                 float* __restrict__ s_i,
                                                 float* __restrict__ s_j,
                                                 int M, int NQ) {
  int tid = threadIdx.x;
  int wv = tid >> 6, lane = tid & 63, qd = lane >> 4, lc = lane & 15;
  int i0 = blockIdx.x * 64;
  int arow = i0 + wv * 16 + lc;
  if (arow >= M) arow = M - 1;  // clamp; stores guarded later
  short8 af[8];
#pragma unroll
  for (int kk = 0; kk < 8; ++kk)
    af[kk] = *(const short8*)(xb + (size_t)arow * 256 + kk * 32 + qd * 8);
  f32x4 acc[16];
#pragma unroll
  for (int jt = 0; jt < 16; ++jt) acc[jt] = (f32x4){0.f, 0.f, 0.f, 0.f};
#pragma unroll
  for (int kk = 0; kk < 8; ++kk) {
#pragma unroll
    for (int half = 0; half < 2; ++half) {
      short8 bf[8];
#pragma unroll
      for (int j = 0; j < 8; ++j)
        bf[j] = *(const short8*)(Wb + (size_t)((half * 8 + j) * 16 + lc) * 256 + kk * 32 + qd * 8);
#pragma unroll
      for (int j = 0; j < 8; ++j)
        acc[half * 8 + j] =
            __builtin_amdgcn_mfma_f32_16x16x32_bf16(af[kk], bf[j], acc[half * 8 + j], 0, 0, 0);
    }
  }
  // constants for the chain
  float y2 = *hb2p;
  float hbreg[16];
#pragma unroll
  for (int jt = 0; jt < 16; ++jt) hbreg[jt] = hb[jt * 16 + lc];

#pragma unroll
  for (int r = 0; r < 4; ++r) {
    int row_r = i0 + wv * 16 + qd * 4 + r;
    bool valid = row_r < M;
    int rr = valid ? row_r : M - 1;
    float rsv = rs[rr];
    float v[16];
    float ss = 0.0f;
#pragma unroll
    for (int jt = 0; jt < 16; ++jt) { v[jt] = rsv * acc[jt][r]; ss += v[jt] * v[jt]; }
    ss = gsum16(ss);
    // expmap0 + proj (analytic norms)
    float n1 = fmaxf(sqrtf(ss), MIN_NORM);
    float e1 = tanhf(n1) / n1;
    float n2 = e1 * n1;                       // |expmap0(v)|
    float f2 = (n2 > MAXN) ? MAXN / n2 : 1.0f;
    float e12 = e1 * f2;
    float nx = n2 * f2;                       // |proj(...)|
    float x2 = nx * nx;
#pragma unroll
    for (int jt = 0; jt < 16; ++jt) v[jt] *= e12;
    // mobius_add(v, hb)
    float xy = 0.0f;
#pragma unroll
    for (int jt = 0; jt < 16; ++jt) xy += v[jt] * hbreg[jt];
    xy = gsum16(xy);
    float c1 = 1.0f + 2.0f * xy + y2;
    float c2 = 1.0f - x2;
    float den = fmaxf(1.0f + 2.0f * xy + x2 * y2, MIN_NORM);
    float inv = 1.0f / den;
    float s3 = inv * inv * (c1 * c1 * x2 + 2.0f * c1 * c2 * xy + c2 * c2 * y2);
    float n3 = fmaxf(sqrtf(s3), MIN_NORM);
    float f3 = (n3 > MAXN) ? MAXN / n3 : 1.0f;
    float n4 = fmaxf(n3 * f3, MIN_NORM);      // |proj(z)| <= MAXN < 1-1e-7
    float sc = atanhf(n4) / n4;
    float g = inv * f3 * sc;
    float Lv[16];
#pragma unroll
    for (int jt = 0; jt < 16; ++jt) Lv[jt] = (c1 * v[jt] + c2 * hbreg[jt]) * g;
    // faithful head/node decode for this Lmat row
    int h_r = row_r / NQ;
    int q_r = row_r - h_r * NQ;
    if (valid) {
#pragma unroll
      for (int jt = 0; jt < 16; ++jt) {
        int n = q_r * 4 + (jt >> 2);
        int d = (jt & 3) * 16 + lc;
        L[(size_t)n * 256 + h_r * 64 + d] = f2bf(Lv[jt]);
      }
    }
    float pig[4], pjg[4];
#pragma unroll
    for (int g4 = 0; g4 < 4; ++g4) {
      float pi = 0.0f, pj = 0.0f;
#pragma unroll
      for (int t = 0; t < 4; ++t) {
        float a_i = att[h_r * 128 + t * 16 + lc];
        float a_j = att[h_r * 128 + 64 + t * 16 + lc];
        pi += Lv[g4 * 4 + t] * a_i;
        pj += Lv[g4 * 4 + t] * a_j;
      }
      pig[g4] = gsum16(pi);
      pjg[g4] = gsum16(pj);
    }
    if (valid && lc == 0) {
#pragma unroll
      for (int g4 = 0; g4 < 4; ++g4) {
        int n = q_r * 4 + g4;
        s_i[n * 4 + h_r] = pig[g4];
        s_j[n * 4 + h_r] = pjg[g4];
      }
    }
  }
}

// ---------------- CSR buckets (ushort slots): self-loop slot 0 (init in k_prep) ---
__global__ void k_fill(const int* __restrict__ ei, int* __restrict__ cnt,
                       unsigned short* __restrict__ slots, int E) {
  int e = blockIdx.x * blockDim.x + threadIdx.x;
  if (e < E) {
    int s = ei[e];
    int d = ei[E + e];
    int pos = atomicAdd(&cnt[d], 1);
    if (pos < 64) slots[(size_t)d * 64 + pos] = (unsigned short)s;
  }
}

// ---------------- aggregation + epilogue; block = q (4 nodes, 4 final rows) -------
// Gather: lane loads 16B (ushort8) => 32 lanes cover one 512B L-row, a wave
// processes 2 edges per load instruction; 8-deep batch = 16 edges in flight.
__global__ __launch_bounds__(256) void HGATLayer_49246095016355_kernel(
    const unsigned short* __restrict__ L,
    const float* __restrict__ s_i,
    const float* __restrict__ s_j,
    const int* __restrict__ cnt,
    const unsigned short* __restrict__ slots,
    const float* __restrict__ b_conv,
    float* __restrict__ out, int N, int NQ) {
  int q = blockIdx.x;
  int w = threadIdx.x >> 6, lane = threadIdx.x & 63;
  int n = q * 4 + w;
  int deg = min(cnt[n], 64);
  float4 si4 = *(const float4*)(s_i + n * 4);
  // lane-parallel per-head scores for edge k=lane
  int src_l = n;  // pad value: valid row, weight 0
  float4 a4 = {-1e30f, -1e30f, -1e30f, -1e30f};
  if (lane < deg) {
    src_l = slots[(size_t)n * 64 + lane];
    float4 sj4 = *(const float4*)(s_j + src_l * 4);
    float t0 = si4.x + sj4.x, t1 = si4.y + sj4.y, t2 = si4.z + sj4.z, t3 = si4.w + sj4.w;
    a4.x = (t0 > 0.f) ? t0 : 0.2f * t0;
    a4.y = (t1 > 0.f) ? t1 : 0.2f * t1;
    a4.z = (t2 > 0.f) ? t2 : 0.2f * t2;
    a4.w = (t3 > 0.f) ? t3 : 0.2f * t3;
  }
  float4 mx = a4;
#pragma unroll
  for (int off = 32; off > 0; off >>= 1) {
    mx.x = fmaxf(mx.x, __shfl_xor(mx.x, off, 64));
    mx.y = fmaxf(mx.y, __shfl_xor(mx.y, off, 64));
    mx.z = fmaxf(mx.z, __shfl_xor(mx.z, off, 64));
    mx.w = fmaxf(mx.w, __shfl_xor(mx.w, off, 64));
  }
  float4 p4 = {0.f, 0.f, 0.f, 0.f};
  if (lane < deg) {
    p4.x = __expf(a4.x - mx.x); p4.y = __expf(a4.y - mx.y);
    p4.z = __expf(a4.z - mx.z); p4.w = __expf(a4.w - mx.w);
  }
  float4 sm = p4;
#pragma unroll
  for (int off = 32; off > 0; off >>= 1) {
    sm.x += __shfl_xor(sm.x, off, 64);
    sm.y += __shfl_xor(sm.y, off, 64);
    sm.z += __shfl_xor(sm.z, off, 64);
    sm.w += __shfl_xor(sm.w, off, 64);
  }
  __shared__ int   s_src[4][64];
  __shared__ float s_w[4][64][4];
  s_src[w][lane] = src_l;
  *(float4*)&s_w[w][lane][0] = p4;  // same-wave produce/consume: no barrier needed

  // new gather layout: c = 16B chunk of row (8 dims), ep = edge parity
  int c = lane & 31, ep = lane >> 5, hc = c >> 3;
  float smh = (hc == 0) ? sm.x : (hc == 1) ? sm.y : (hc == 2) ? sm.z : sm.w;

  float accv[8];
#pragma unroll
  for (int j = 0; j < 8; ++j) accv[j] = 0.f;
  int np2 = (deg + 1) >> 1;        // pairs of edges
  int nb = (np2 + 7) >> 3;         // batches of 8 pairs (16 edges); nb <= 4
  for (int b = 0; b < nb; ++b) {
    int kbase = b * 16 + ep;       // edge slot for pair p: kbase + 2*p  (<= 63)
    int ks[8];
#pragma unroll
    for (int p = 0; p < 8; ++p) ks[p] = s_src[w][kbase + 2 * p];
    short8 r[8];
#pragma unroll
    for (int p = 0; p < 8; ++p)
      r[p] = *(const short8*)(L + (size_t)ks[p] * 256 + c * 8);
    float wk[8];
#pragma unroll
    for (int p = 0; p < 8; ++p) wk[p] = s_w[w][kbase + 2 * p][hc];
#pragma unroll
    for (int p = 0; p < 8; ++p) {
#pragma unroll
      for (int j = 0; j < 8; ++j)
        accv[j] = fmaf(wk[p], bf2f((unsigned short)r[p][j]), accv[j]);
    }
  }
  // combine the two edge-parity halves (lanes l and l^32 hold same dims)
#pragma unroll
  for (int j = 0; j < 8; ++j) accv[j] += __shfl_xor(accv[j], 32, 64);

  float isum = 1.0f / fmaxf(smh, MIN_NORM);
  const float* bcp = b_conv + w * 64 + (c & 7) * 8;
  float vv[8];
  float ps = 0.f;
#pragma unroll
  for (int j = 0; j < 8; ++j) {
    float t = fmaxf(accv[j] * isum + bcp[j], 0.0f);
    vv[j] = t;
    ps += t * t;
  }
  // reduce ps over the 8 lanes of this head group (c in [hc*8, hc*8+8))
#pragma unroll
  for (int off = 1; off < 8; off <<= 1) ps += __shfl_xor(ps, off, 64);
  __shared__ float red[4][4];
  if (lane < 32 && (c & 7) == 0) red[w][hc] = ps;
  __syncthreads();
  float tot = red[0][hc] + red[1][hc] + red[2][hc] + red[3][hc];
  float nraw = sqrtf(tot);
  float ncl = fmaxf(nraw, MIN_NORM);
  float t = tanhf(ncl) / ncl;  // expmap0 scale
  float ny = fmaxf(t * nraw, MIN_NORM);
  float f = (ny > MAXN) ? (MAXN / ny) : 1.0f;
  float tf = t * f;
  if (lane < 32) {
    float4 y0; y0.x = tf * vv[0]; y0.y = tf * vv[1]; y0.z = tf * vv[2]; y0.w = tf * vv[3];
    float4 y1; y1.x = tf * vv[4]; y1.y = tf * vv[5]; y1.z = tf * vv[6]; y1.w = tf * vv[7];
    float* op = out + (size_t)(hc * NQ + q) * 256 + w * 64 + (c & 7) * 8;
    *(float4*)op = y0;
    *(float4*)(op + 4) = y1;
  }
}

extern "C" void kernel_launch(void* const* d_in, const int* in_sizes, int n_in,
                              void* d_out, int out_size, void* d_ws, size_t ws_size,
                              hipStream_t stream) {
  const float* x   = (const float*)d_in[0];
  const int*   ei  = (const int*)d_in[1];
  const float* W   = (const float*)d_in[2];
  const float* bl  = (const float*)d_in[3];
  const float* att = (const float*)d_in[4];
  const float* bc  = (const float*)d_in[5];
  float* out = (float*)d_out;

  const int N = in_sizes[0] / 256;  // 50000
  const int E = in_sizes[1] / 2;    // 800000
  const int NQ = N / 4;             // 12500

  // xb (bf16 x) staged in d_out: dead before the final kernel overwrites out
  unsigned short* xb = (unsigned short*)d_out;

  char* w = (char*)d_ws;
  unsigned short* L  = (unsigned short*)w; w += (size_t)N * 256 * 2;  // 25.6 MB node-major
  unsigned short* Wb = (unsigned short*)w; w += 65536 * 2;            // 128 KB
  float* s_i = (float*)w; w += (size_t)N * 4 * 4;
  float* s_j = (float*)w; w += (size_t)N * 4 * 4;
  float* rs  = (float*)w; w += (size_t)N * 4;
  float* hb  = (float*)w; w += 256 * 4;
  float* hb2 = (float*)w; w += 16;
  int* cnt   = (int*)w;   w += (size_t)N * 4;
  unsigned short* slots = (unsigned short*)w;  // N*64 ushort = 6.4 MB

  k_prep<<<N / 4, 256, 0, stream>>>(x, W, bl, rs, xb, Wb, hb, hb2, cnt, slots, N);
  k_gemmhyp<<<(N + 63) / 64, 256, 0, stream>>>(xb, Wb, rs, hb, hb2, att, L, s_i, s_j, N, NQ);
  k_fill<<<(E + 255) / 256, 256, 0, stream>>>(ei, cnt, slots, E);
  HGATLayer_49246095016355_kernel<<<NQ, 256, 0, stream>>>(L, s_i, s_j, cnt, slots, bc, out, N, NQ);
}

// Round 3
// 254.435 us; speedup vs baseline: 1.2201x; 1.2043x over previous
//
#include <hip/hip_runtime.h>

#define MIN_NORM 1e-15f
#define MAXN (1.0f - 4e-3f)

typedef __attribute__((ext_vector_type(8))) short short8;   // 8 bf16 (4 VGPRs)
typedef __attribute__((ext_vector_type(4))) float f32x4;    // 4 fp32 acc

__device__ __forceinline__ float bf2f(unsigned short u) {
  union { unsigned int i; float f; } c; c.i = ((unsigned int)u) << 16; return c.f;
}
__device__ __forceinline__ unsigned short f2bf(float f) {
  union { float f; unsigned int i; } c; c.f = f;
  unsigned int r = c.i + 0x7FFFu + ((c.i >> 16) & 1u);
  return (unsigned short)(r >> 16);
}
__device__ __forceinline__ float wave_sum(float v) {
#pragma unroll
  for (int off = 32; off > 0; off >>= 1) v += __shfl_xor(v, off, 64);
  return v;
}
__device__ __forceinline__ float gsum16(float v) {  // sum over 16-lane group
#pragma unroll
  for (int off = 8; off > 0; off >>= 1) v += __shfl_xor(v, off, 64);
  return v;
}

// ---------------- prep: rs[i] + bf16 cast of x; W->bf16 fragment-major (blocks<32);
// ---------------- hb (block 64); CSR init (cnt=1, self-loop slot 0) ----------------
__global__ __launch_bounds__(256) void k_prep(const float* __restrict__ x,
                                              const float* __restrict__ W,
                                              const float* __restrict__ b_lin,
                                              float* __restrict__ rs,
                                              unsigned short* __restrict__ xb,
                                              unsigned short* __restrict__ Wb,
                                              float* __restrict__ hb,
                                              float* __restrict__ hb2,
                                              int* __restrict__ cnt,
                                              unsigned short* __restrict__ slots, int N) {
  int row = blockIdx.x * 4 + (threadIdx.x >> 6);
  int lane = threadIdx.x & 63;
  float4 u = *(const float4*)(x + (size_t)row * 256 + lane * 4);
  ushort4 st;
  st.x = f2bf(u.x); st.y = f2bf(u.y); st.z = f2bf(u.z); st.w = f2bf(u.w);
  *(ushort4*)(xb + (size_t)row * 256 + lane * 4) = st;
  float s = wave_sum(u.x * u.x + u.y * u.y + u.z * u.z + u.w * u.w);
  if (lane == 0) {
    float n = fmaxf(sqrtf(s), MIN_NORM);
    rs[row] = atanhf(fminf(n, 1.0f - 1e-7f)) / n;
  }
  // CSR init folded in: cnt=1, slot 0 = self loop
  int g = blockIdx.x * 256 + threadIdx.x;
  if (g < N) { cnt[g] = 1; slots[(size_t)g * 64] = (unsigned short)g; }
  // W -> bf16 in FRAGMENT-MAJOR layout for coalesced gemm loads:
  // Wb[ ((kk*2+half)*8 + j)*64 + lane ]*8  <-  W[ ((half*8+j)*16+lc)*256 + kk*32 + qd*8 .. +8 ]
  if (blockIdx.x < 32) {
    int g2 = blockIdx.x * 256 + threadIdx.x;   // 0..8191
    int ln = g2 & 63, fj = g2 >> 6;            // fj = (kk*2+half)*8 + j
    int kk = fj >> 4, hf = (fj >> 3) & 1, j = fj & 7;
    int lc2 = ln & 15, qd2 = ln >> 4;
    const float* src = W + (size_t)(((hf * 8 + j) * 16 + lc2) * 256 + kk * 32 + qd2 * 8);
    float4 a = *(const float4*)src;
    float4 b = *(const float4*)(src + 4);
    unsigned short* dst = Wb + (size_t)g2 * 8;
    dst[0] = f2bf(a.x); dst[1] = f2bf(a.y); dst[2] = f2bf(a.z); dst[3] = f2bf(a.w);
    dst[4] = f2bf(b.x); dst[5] = f2bf(b.y); dst[6] = f2bf(b.z); dst[7] = f2bf(b.w);
  }
  // hb = proj(expmap0(b_lin)) + |hb|^2, one wave
  if (blockIdx.x == 64 && threadIdx.x < 64) {
    float4 b4 = ((const float4*)b_lin)[lane];
    float bx = b4.x, by = b4.y, bz = b4.z, bw = b4.w;
    float sb = wave_sum(bx * bx + by * by + bz * bz + bw * bw);
    float n1 = fmaxf(sqrtf(sb), MIN_NORM);
    float t = tanhf(n1) / n1;
    bx *= t; by *= t; bz *= t; bw *= t;
    float s2 = wave_sum(bx * bx + by * by + bz * bz + bw * bw);
    float n2 = fmaxf(sqrtf(s2), MIN_NORM);
    if (n2 > MAXN) { float f = MAXN / n2; bx *= f; by *= f; bz *= f; bw *= f; }
    float4 o; o.x = bx; o.y = by; o.z = bz; o.w = bw;
    ((float4*)hb)[lane] = o;
    float s3 = wave_sum(bx * bx + by * by + bz * bz + bw * bw);
    if (lane == 0) *hb2 = s3;
  }
}

// ---------------- fused MFMA GEMM + hyperbolic chain + attention partials ----------
// ---------------- PLUS CSR fill role (blocks >= GB): overlaps latency-bound --------
// ---------------- scatter with compute-bound gemm on the same device --------------
__global__ __launch_bounds__(256) void k_gemmfill(const unsigned short* __restrict__ xb,
                                                  const unsigned short* __restrict__ Wb,
                                                  const float* __restrict__ rs,
                                                  const float* __restrict__ hb,
                                                  const float* __restrict__ hb2p,
                                                  const float* __restrict__ att,
                                                  unsigned short* __restrict__ L,
                                                  float* __restrict__ s_i,
                                                  float* __restrict__ s_j,
                                                  const int* __restrict__ ei,
                                                  int* __restrict__ cnt,
                                                  unsigned short* __restrict__ slots,
                                                  int E, int GB, int M, int NQ) {
  if (blockIdx.x >= GB) {
    // ---- fill role: CSR bucket scatter (latency/MSHR-bound) ----
    int e = (blockIdx.x - GB) * 256 + threadIdx.x;
    if (e < E) {
      int s = ei[e];
      int d = ei[E + e];
      int pos = atomicAdd(&cnt[d], 1);
      if (pos < 64) slots[(size_t)d * 64 + pos] = (unsigned short)s;
    }
    return;
  }
  int tid = threadIdx.x;
  int wv = tid >> 6, lane = tid & 63, qd = lane >> 4, lc = lane & 15;
  int i0 = blockIdx.x * 64;
  int arow = i0 + wv * 16 + lc;
  if (arow >= M) arow = M - 1;  // clamp; stores guarded later
  short8 af[8];
#pragma unroll
  for (int kk = 0; kk < 8; ++kk)
    af[kk] = *(const short8*)(xb + (size_t)arow * 256 + kk * 32 + qd * 8);
  f32x4 acc[16];
#pragma unroll
  for (int jt = 0; jt < 16; ++jt) acc[jt] = (f32x4){0.f, 0.f, 0.f, 0.f};
#pragma unroll
  for (int kk = 0; kk < 8; ++kk) {
#pragma unroll
    for (int half = 0; half < 2; ++half) {
      short8 bf[8];
#pragma unroll
      for (int j = 0; j < 8; ++j)
        bf[j] = *(const short8*)(Wb + (size_t)(((kk * 2 + half) * 8 + j) * 64 + lane) * 8);
#pragma unroll
      for (int j = 0; j < 8; ++j)
        acc[half * 8 + j] =
            __builtin_amdgcn_mfma_f32_16x16x32_bf16(af[kk], bf[j], acc[half * 8 + j], 0, 0, 0);
    }
  }
  // constants for the chain
  float y2 = *hb2p;
  float hbreg[16];
#pragma unroll
  for (int jt = 0; jt < 16; ++jt) hbreg[jt] = hb[jt * 16 + lc];

#pragma unroll
  for (int r = 0; r < 4; ++r) {
    int row_r = i0 + wv * 16 + qd * 4 + r;
    bool valid = row_r < M;
    int rr = valid ? row_r : M - 1;
    float rsv = rs[rr];
    float v[16];
    float ss = 0.0f;
#pragma unroll
    for (int jt = 0; jt < 16; ++jt) { v[jt] = rsv * acc[jt][r]; ss += v[jt] * v[jt]; }
    ss = gsum16(ss);
    // expmap0 + proj (analytic norms)
    float n1 = fmaxf(sqrtf(ss), MIN_NORM);
    float e1 = tanhf(n1) / n1;
    float n2 = e1 * n1;                       // |expmap0(v)|
    float f2 = (n2 > MAXN) ? MAXN / n2 : 1.0f;
    float e12 = e1 * f2;
    float nx = n2 * f2;                       // |proj(...)|
    float x2 = nx * nx;
#pragma unroll
    for (int jt = 0; jt < 16; ++jt) v[jt] *= e12;
    // mobius_add(v, hb)
    float xy = 0.0f;
#pragma unroll
    for (int jt = 0; jt < 16; ++jt) xy += v[jt] * hbreg[jt];
    xy = gsum16(xy);
    float c1 = 1.0f + 2.0f * xy + y2;
    float c2 = 1.0f - x2;
    float den = fmaxf(1.0f + 2.0f * xy + x2 * y2, MIN_NORM);
    float inv = 1.0f / den;
    float s3 = inv * inv * (c1 * c1 * x2 + 2.0f * c1 * c2 * xy + c2 * c2 * y2);
    float n3 = fmaxf(sqrtf(s3), MIN_NORM);
    float f3 = (n3 > MAXN) ? MAXN / n3 : 1.0f;
    float n4 = fmaxf(n3 * f3, MIN_NORM);      // |proj(z)| <= MAXN < 1-1e-7
    float sc = atanhf(n4) / n4;
    float g = inv * f3 * sc;
    float Lv[16];
#pragma unroll
    for (int jt = 0; jt < 16; ++jt) Lv[jt] = (c1 * v[jt] + c2 * hbreg[jt]) * g;
    // faithful head/node decode for this Lmat row
    int h_r = row_r / NQ;
    int q_r = row_r - h_r * NQ;
    if (valid) {
#pragma unroll
      for (int jt = 0; jt < 16; ++jt) {
        int n = q_r * 4 + (jt >> 2);
        int d = (jt & 3) * 16 + lc;
        L[(size_t)n * 256 + h_r * 64 + d] = f2bf(Lv[jt]);
      }
    }
    float pig[4], pjg[4];
#pragma unroll
    for (int g4 = 0; g4 < 4; ++g4) {
      float pi = 0.0f, pj = 0.0f;
#pragma unroll
      for (int t = 0; t < 4; ++t) {
        float a_i = att[h_r * 128 + t * 16 + lc];
        float a_j = att[h_r * 128 + 64 + t * 16 + lc];
        pi += Lv[g4 * 4 + t] * a_i;
        pj += Lv[g4 * 4 + t] * a_j;
      }
      pig[g4] = gsum16(pi);
      pjg[g4] = gsum16(pj);
    }
    if (valid && lc == 0) {
#pragma unroll
      for (int g4 = 0; g4 < 4; ++g4) {
        int n = q_r * 4 + g4;
        s_i[n * 4 + h_r] = pig[g4];
        s_j[n * 4 + h_r] = pjg[g4];
      }
    }
  }
}

// ---------------- aggregation + epilogue; block = q (4 nodes, 4 final rows) -------
// Gather: lane loads 16B (ushort8) => 32 lanes cover one 512B L-row, a wave
// processes 2 edges per load instruction; 8-deep batch = 16 edges in flight.
__global__ __launch_bounds__(256) void HGATLayer_49246095016355_kernel(
    const unsigned short* __restrict__ L,
    const float* __restrict__ s_i,
    const float* __restrict__ s_j,
    const int* __restrict__ cnt,
    const unsigned short* __restrict__ slots,
    const float* __restrict__ b_conv,
    float* __restrict__ out, int N, int NQ) {
  int q = blockIdx.x;
  int w = threadIdx.x >> 6, lane = threadIdx.x & 63;
  int n = q * 4 + w;
  int deg = min(cnt[n], 64);
  float4 si4 = *(const float4*)(s_i + n * 4);
  // lane-parallel per-head scores for edge k=lane
  int src_l = n;  // pad value: valid row, weight 0
  float4 a4 = {-1e30f, -1e30f, -1e30f, -1e30f};
  if (lane < deg) {
    src_l = slots[(size_t)n * 64 + lane];
    float4 sj4 = *(const float4*)(s_j + src_l * 4);
    float t0 = si4.x + sj4.x, t1 = si4.y + sj4.y, t2 = si4.z + sj4.z, t3 = si4.w + sj4.w;
    a4.x = (t0 > 0.f) ? t0 : 0.2f * t0;
    a4.y = (t1 > 0.f) ? t1 : 0.2f * t1;
    a4.z = (t2 > 0.f) ? t2 : 0.2f * t2;
    a4.w = (t3 > 0.f) ? t3 : 0.2f * t3;
  }
  float4 mx = a4;
#pragma unroll
  for (int off = 32; off > 0; off >>= 1) {
    mx.x = fmaxf(mx.x, __shfl_xor(mx.x, off, 64));
    mx.y = fmaxf(mx.y, __shfl_xor(mx.y, off, 64));
    mx.z = fmaxf(mx.z, __shfl_xor(mx.z, off, 64));
    mx.w = fmaxf(mx.w, __shfl_xor(mx.w, off, 64));
  }
  float4 p4 = {0.f, 0.f, 0.f, 0.f};
  if (lane < deg) {
    p4.x = __expf(a4.x - mx.x); p4.y = __expf(a4.y - mx.y);
    p4.z = __expf(a4.z - mx.z); p4.w = __expf(a4.w - mx.w);
  }
  float4 sm = p4;
#pragma unroll
  for (int off = 32; off > 0; off >>= 1) {
    sm.x += __shfl_xor(sm.x, off, 64);
    sm.y += __shfl_xor(sm.y, off, 64);
    sm.z += __shfl_xor(sm.z, off, 64);
    sm.w += __shfl_xor(sm.w, off, 64);
  }
  __shared__ int   s_src[4][64];
  __shared__ float s_w[4][64][4];
  s_src[w][lane] = src_l;
  *(float4*)&s_w[w][lane][0] = p4;  // same-wave produce/consume: no barrier needed

  // gather layout: c = 16B chunk of row (8 dims), ep = edge parity
  int c = lane & 31, ep = lane >> 5, hc = c >> 3;
  float smh = (hc == 0) ? sm.x : (hc == 1) ? sm.y : (hc == 2) ? sm.z : sm.w;

  float accv[8];
#pragma unroll
  for (int j = 0; j < 8; ++j) accv[j] = 0.f;
  int np2 = (deg + 1) >> 1;        // pairs of edges
  int nb = (np2 + 7) >> 3;         // batches of 8 pairs (16 edges); nb <= 4
  for (int b = 0; b < nb; ++b) {
    int kbase = b * 16 + ep;       // edge slot for pair p: kbase + 2*p  (<= 63)
    int ks[8];
#pragma unroll
    for (int p = 0; p < 8; ++p) ks[p] = s_src[w][kbase + 2 * p];
    short8 r[8];
#pragma unroll
    for (int p = 0; p < 8; ++p)
      r[p] = *(const short8*)(L + (size_t)ks[p] * 256 + c * 8);
    float wk[8];
#pragma unroll
    for (int p = 0; p < 8; ++p) wk[p] = s_w[w][kbase + 2 * p][hc];
#pragma unroll
    for (int p = 0; p < 8; ++p) {
#pragma unroll
      for (int j = 0; j < 8; ++j)
        accv[j] = fmaf(wk[p], bf2f((unsigned short)r[p][j]), accv[j]);
    }
  }
  // combine the two edge-parity halves (lanes l and l^32 hold same dims)
#pragma unroll
  for (int j = 0; j < 8; ++j) accv[j] += __shfl_xor(accv[j], 32, 64);

  float isum = 1.0f / fmaxf(smh, MIN_NORM);
  const float* bcp = b_conv + w * 64 + (c & 7) * 8;
  float vv[8];
  float ps = 0.f;
#pragma unroll
  for (int j = 0; j < 8; ++j) {
    float t = fmaxf(accv[j] * isum + bcp[j], 0.0f);
    vv[j] = t;
    ps += t * t;
  }
  // reduce ps over the 8 lanes of this head group (c in [hc*8, hc*8+8))
#pragma unroll
  for (int off = 1; off < 8; off <<= 1) ps += __shfl_xor(ps, off, 64);
  __shared__ float red[4][4];
  if (lane < 32 && (c & 7) == 0) red[w][hc] = ps;
  __syncthreads();
  float tot = red[0][hc] + red[1][hc] + red[2][hc] + red[3][hc];
  float nraw = sqrtf(tot);
  float ncl = fmaxf(nraw, MIN_NORM);
  float t = tanhf(ncl) / ncl;  // expmap0 scale
  float ny = fmaxf(t * nraw, MIN_NORM);
  float f = (ny > MAXN) ? (MAXN / ny) : 1.0f;
  float tf = t * f;
  if (lane < 32) {
    float4 y0; y0.x = tf * vv[0]; y0.y = tf * vv[1]; y0.z = tf * vv[2]; y0.w = tf * vv[3];
    float4 y1; y1.x = tf * vv[4]; y1.y = tf * vv[5]; y1.z = tf * vv[6]; y1.w = tf * vv[7];
    float* op = out + (size_t)(hc * NQ + q) * 256 + w * 64 + (c & 7) * 8;
    *(float4*)op = y0;
    *(float4*)(op + 4) = y1;
  }
}

extern "C" void kernel_launch(void* const* d_in, const int* in_sizes, int n_in,
                              void* d_out, int out_size, void* d_ws, size_t ws_size,
                              hipStream_t stream) {
  const float* x   = (const float*)d_in[0];
  const int*   ei  = (const int*)d_in[1];
  const float* W   = (const float*)d_in[2];
  const float* bl  = (const float*)d_in[3];
  const float* att = (const float*)d_in[4];
  const float* bc  = (const float*)d_in[5];
  float* out = (float*)d_out;

  const int N = in_sizes[0] / 256;  // 50000
  const int E = in_sizes[1] / 2;    // 800000
  const int NQ = N / 4;             // 12500

  // xb (bf16 x) staged in d_out: dead before the final kernel overwrites out
  unsigned short* xb = (unsigned short*)d_out;

  char* w = (char*)d_ws;
  unsigned short* L  = (unsigned short*)w; w += (size_t)N * 256 * 2;  // 25.6 MB node-major
  unsigned short* Wb = (unsigned short*)w; w += 65536 * 2;            // 128 KB fragment-major
  float* s_i = (float*)w; w += (size_t)N * 4 * 4;
  float* s_j = (float*)w; w += (size_t)N * 4 * 4;
  float* rs  = (float*)w; w += (size_t)N * 4;
  float* hb  = (float*)w; w += 256 * 4;
  float* hb2 = (float*)w; w += 16;
  int* cnt   = (int*)w;   w += (size_t)N * 4;
  unsigned short* slots = (unsigned short*)w;  // N*64 ushort = 6.4 MB

  const int GB = (N + 63) / 64;        // gemm-role blocks
  const int FB = (E + 255) / 256;      // fill-role blocks

  k_prep<<<N / 4, 256, 0, stream>>>(x, W, bl, rs, xb, Wb, hb, hb2, cnt, slots, N);
  k_gemmfill<<<GB + FB, 256, 0, stream>>>(xb, Wb, rs, hb, hb2, att, L, s_i, s_j,
                                          ei, cnt, slots, E, GB, N, NQ);
  HGATLayer_49246095016355_kernel<<<NQ, 256, 0, stream>>>(L, s_i, s_j, cnt, slots, bc, out, N, NQ);
}